// Round 10
// baseline (517.927 us; speedup 1.0000x reference)
//
#include <hip/hip_runtime.h>

#define MM 1024
#define NE 100000
#define KD 256
#define NT 782       // fallback tiling
#define NSTRIP 16
#define ESTRIP 6400
#define PSTRIDE 784

typedef __attribute__((ext_vector_type(8))) short bf16x8;
typedef __attribute__((ext_vector_type(4))) float f32x4;
typedef __attribute__((ext_vector_type(4))) short short4v;

// ws layout (bytes):
//   [0, 524288)            hr bf16      1024*256*2
//   [524288, 528384)       hr_sq f32    1024
//   [528384, 928384)       ent_sq f32   100000
//   [1048576, 7471104)     argmax partials u64 [1024][784]
//   [8388608, +51.2MB)     ent bf16     100000*256*2   (tier A only)
#define WS_HRSQ   524288
#define WS_ENTSQ  528384
#define WS_PART   1048576
#define WS_ENTB   8388608
#define WS_NEED   (WS_ENTB + (size_t)NE * KD * 2)

#define AS1 __attribute__((address_space(1)))
#define AS3 __attribute__((address_space(3)))

__device__ __forceinline__ void gld_lds16(const void* g, void* l) {
    __builtin_amdgcn_global_load_lds((const AS1 unsigned int*)g,
                                     (AS3 unsigned int*)l, 16, 0, 0);
}

__device__ __forceinline__ unsigned short f2bf(float f) {
    union { float f; unsigned int u; } v; v.f = f;
    unsigned int u = v.u;
    return (unsigned short)((u + 0x7FFFu + ((u >> 16) & 1u)) >> 16);
}

__device__ __forceinline__ bf16x8 pack8(float4 a, float4 b) {
    bf16x8 t;
    t[0] = (short)f2bf(a.x); t[1] = (short)f2bf(a.y);
    t[2] = (short)f2bf(a.z); t[3] = (short)f2bf(a.w);
    t[4] = (short)f2bf(b.x); t[5] = (short)f2bf(b.y);
    t[6] = (short)f2bf(b.z); t[7] = (short)f2bf(b.w);
    return t;
}

// monotonic pack: bigger score -> bigger key; ties -> smaller col wins
__device__ __forceinline__ unsigned long long packkey(float s, int col) {
    unsigned int u = __float_as_uint(s);
    unsigned int key = u ^ ((unsigned int)((int)u >> 31) | 0x80000000u);
    return ((unsigned long long)key << 32) | (unsigned int)(~col);
}

// raw barrier: LDS visibility only — NO vmcnt drain (keeps stores in flight)
__device__ __forceinline__ void bar_lgkm() {
    asm volatile("s_waitcnt lgkmcnt(0)" ::: "memory");
    __builtin_amdgcn_s_barrier();
    asm volatile("" ::: "memory");
}

// ---- prep: hr = E[head] + R[rel] -> bf16; hr_sq ----
__global__ __launch_bounds__(64) void prep_kernel(const int* __restrict__ q,
                                                  const float* __restrict__ ent,
                                                  const float* __restrict__ rel,
                                                  unsigned short* __restrict__ hrb,
                                                  float* __restrict__ hrsq) {
    int b = blockIdx.x;
    int lane = threadIdx.x;
    int head = q[b * 3 + 0];
    int r    = q[b * 3 + 1];
    float4 e  = ((const float4*)(ent + (size_t)head * KD))[lane];
    float4 rv = ((const float4*)(rel + (size_t)r * KD))[lane];
    float4 h; h.x = e.x + rv.x; h.y = e.y + rv.y; h.z = e.z + rv.z; h.w = e.w + rv.w;
    short4v hv;
    hv[0] = (short)f2bf(h.x); hv[1] = (short)f2bf(h.y);
    hv[2] = (short)f2bf(h.z); hv[3] = (short)f2bf(h.w);
    *(short4v*)(hrb + (size_t)b * KD + lane * 4) = hv;
    float sq = h.x * h.x + h.y * h.y + h.z * h.z + h.w * h.w;
    #pragma unroll
    for (int off = 32; off > 0; off >>= 1) sq += __shfl_down(sq, off, 64);
    if (lane == 0) hrsq[b] = sq;
}

// ---- fused: ent f32 -> bf16 + ent_sq ----
__global__ __launch_bounds__(256) void conv_entsq_kernel(const float* __restrict__ ent,
                                                         unsigned short* __restrict__ entb,
                                                         float* __restrict__ entsq) {
    int gw   = (blockIdx.x * 256 + threadIdx.x) >> 6;
    int lane = threadIdx.x & 63;
    int row  = gw * 2 + (lane >> 5);
    if (row >= NE) return;
    const float4* src = (const float4*)(ent + (size_t)row * KD) + (lane & 31) * 2;
    float4 a = src[0], b = src[1];
    *(bf16x8*)(entb + (size_t)row * KD + (lane & 31) * 8) = pack8(a, b);
    float s = a.x * a.x + a.y * a.y + a.z * a.z + a.w * a.w
            + b.x * b.x + b.y * b.y + b.z * b.z + b.w * b.w;
    #pragma unroll
    for (int off = 16; off > 0; off >>= 1) s += __shfl_xor(s, off, 64);
    if ((lane & 31) == 0) entsq[row] = s;
}

// ---- ent_sq only (fallback path) ----
__global__ __launch_bounds__(256) void entsq_kernel(const float* __restrict__ ent,
                                                    float* __restrict__ entsq) {
    int w = threadIdx.x >> 6, lane = threadIdx.x & 63;
    int n = blockIdx.x * 4 + w;
    if (n >= NE) return;
    float4 v = ((const float4*)(ent + (size_t)n * KD))[lane];
    float s = v.x * v.x + v.y * v.y + v.z * v.z + v.w * v.w;
    #pragma unroll
    for (int off = 32; off > 0; off >>= 1) s += __shfl_down(s, off, 64);
    if (lane == 0) entsq[n] = s;
}

// ---- GEMM v10: producer/consumer wave split. 512 threads:
//      waves 0-3 COMPUTE (vmcnt queue = loads only): MFMA 16q x 64e per iter,
//        epilogue -> LDS tile (dbuf).
//      waves 4-7 STORE (vmcnt queue = stores only): ds_read tile -> 1KB-
//        contiguous row stores + in-register argmax. Stores are never
//        drained inside the loop (raw s_barrier + lgkmcnt only).
//      Geometry: 16q x 6400e strips, strip sharers co-located per XCD. ----
__global__ __launch_bounds__(512, 4) void gemm_v10(const unsigned short* __restrict__ hrb,
                                                   const unsigned short* __restrict__ entb,
                                                   const float* __restrict__ hrsq,
                                                   const float* __restrict__ entsq,
                                                   float* __restrict__ out,
                                                   unsigned long long* __restrict__ part) {
    __shared__ __align__(16) char SMEM[40960];   // [0,8K)=Qs [8K,24K)=tb0 [24K,40K)=tb1

    const int bid   = blockIdx.x;
    const int qg    = bid >> 4;          // 64 query groups of 16
    const int strip = bid & 15;          // XCD = bid%8 = strip%8 -> sharers co-located
    const int q0    = qg * 16;
    const int estart = strip * ESTRIP;
    const int eend   = (estart + ESTRIP < NE) ? (estart + ESTRIP) : NE;
    const int nIter  = (eend - estart + 255) >> 8;

    const int tid  = threadIdx.x;
    const int lane = tid & 63;
    const int wid  = tid >> 6;
    const int lr = lane & 15;
    const int lg = lane >> 4;
    const int lk = lg * 8;

    // ---- stage Q panel: 512 threads x 16B = 8KB, one shot ----
    {
        int L = wid * 1024 + lane * 16;
        int row = L >> 9;
        int G = L ^ ((row & 7) << 4);
        const void* src = (const char*)hrb + (size_t)(q0 + row) * 512 + (G & 511);
        gld_lds16(src, SMEM + wid * 1024);   // wave-uniform dst; HW adds lane*16
    }
    __syncthreads();   // drains Q staging (only Q loads in flight here)

    if (wid < 4) {
        // ================= COMPUTE waves =================
        const float hq = hrsq[q0 + lr];
        for (int it = 0; it <= nIter; ++it) {
            if (it < nIter) {
                const int e_it = estart + it * 256;
                const int e_w  = e_it + wid * 64;

                const unsigned short* aP[4];
                #pragma unroll
                for (int t = 0; t < 4; ++t) {
                    int er = e_w + t * 16 + lr;
                    er = er < NE ? er : (NE - 1);
                    aP[t] = entb + (size_t)er * KD + lk;
                }

                f32x4 acc[4];
                #pragma unroll
                for (int t = 0; t < 4; ++t) acc[t] = (f32x4){0.f, 0.f, 0.f, 0.f};

                #pragma unroll
                for (int ks = 0; ks < 8; ++ks) {
                    int byte = lr * 512 + ((ks * 64 + lg * 16) ^ ((lr & 7) << 4));
                    bf16x8 qf = *(const bf16x8*)((const char*)SMEM + byte);
                    bf16x8 af[4];
                    #pragma unroll
                    for (int t = 0; t < 4; ++t)
                        af[t] = *(const bf16x8*)(aP[t] + ks * 32);
                    #pragma unroll
                    for (int t = 0; t < 4; ++t)
                        acc[t] = __builtin_amdgcn_mfma_f32_16x16x32_bf16(af[t], qf, acc[t], 0, 0, 0);
                }

                // epilogue: scores -> LDS tile (swizzled rows of 1KB)
                char* tbw = SMEM + 8192 + (it & 1) * 16384;
                #pragma unroll
                for (int t = 0; t < 4; ++t) {
                    const int eb = e_w + t * 16 + lg * 4;
                    const int ebc = (eb < NE) ? eb : (NE - 4);
                    const float4 eq = *(const float4*)(entsq + ebc);
                    float4 sv;
                    sv.x = 2.0f * acc[t][0] - hq - eq.x;
                    sv.y = 2.0f * acc[t][1] - hq - eq.y;
                    sv.z = 2.0f * acc[t][2] - hq - eq.z;
                    sv.w = 2.0f * acc[t][3] - hq - eq.w;
                    int off = (wid * 256 + t * 64 + lg * 16) ^ ((lr & 7) << 4);
                    *(float4*)(tbw + lr * 1024 + off) = sv;
                }
            }
            bar_lgkm();
        }
    } else {
        // ================= STORE waves =================
        const int sw = wid - 4;          // owns query rows sw*4 .. sw*4+3
        float bf_[4];
        int   bc_[4];
        #pragma unroll
        for (int i = 0; i < 4; ++i) { bf_[i] = -3.4e38f; bc_[i] = 0; }

        for (int it = 0; it <= nIter; ++it) {
            if (it > 0) {
                const int e_prev = estart + (it - 1) * 256;
                const char* tbr = SMEM + 8192 + ((it - 1) & 1) * 16384;
                const int ec = e_prev + lane * 4;
                #pragma unroll
                for (int i = 0; i < 4; ++i) {
                    int r  = sw * 4 + i;
                    int rb = r * 1024 + ((lane * 16) ^ ((r & 7) << 4));
                    float4 v = *(const float4*)(tbr + rb);
                    if (ec < NE) {
                        *(float4*)(out + (unsigned)(q0 + r) * (unsigned)NE + (unsigned)ec) = v;
                        if (v.x > bf_[i]) { bf_[i] = v.x; bc_[i] = ec; }
                        if (v.y > bf_[i]) { bf_[i] = v.y; bc_[i] = ec + 1; }
                        if (v.z > bf_[i]) { bf_[i] = v.z; bc_[i] = ec + 2; }
                        if (v.w > bf_[i]) { bf_[i] = v.w; bc_[i] = ec + 3; }
                    }
                }
            }
            bar_lgkm();
        }

        // per-row argmax: full-wave reduce, lane0 writes partial
        #pragma unroll
        for (int i = 0; i < 4; ++i) {
            unsigned long long best = packkey(bf_[i], bc_[i]);
            #pragma unroll
            for (int off = 1; off < 64; off <<= 1) {
                unsigned long long o =
                    (unsigned long long)__shfl_xor((long long)best, off, 64);
                best = (o > best) ? o : best;
            }
            if (lane == 0)
                part[(size_t)(q0 + sw * 4 + i) * PSTRIDE + strip] = best;
        }
    }
}

// ---- fallback GEMM (B from f32 directly), atomic-free partials ----
__global__ __launch_bounds__(256, 3) void gemm_direct_f32(const unsigned short* __restrict__ hrb,
                                                          const float* __restrict__ entf,
                                                          const float* __restrict__ hrsq,
                                                          const float* __restrict__ entsq,
                                                          float* __restrict__ out,
                                                          unsigned long long* __restrict__ part) {
    __shared__ unsigned long long lds_best[2][128];
    const int bid  = blockIdx.x;
    const int wgid = (bid & 7) * NT + (bid >> 3);
    const int mt = wgid & 7, nt = wgid >> 3;
    const int m0 = mt * 128, n0 = nt * 128;
    const int tid  = threadIdx.x;
    const int lane = tid & 63;
    const int wid  = tid >> 6;
    const int wr = wid >> 1, wc = wid & 1;
    const int lr = lane & 15;
    const int lk = (lane >> 4) * 8;

    const unsigned short* aP[4];
    const float*          bPf[4];
    int  cg[4];
    bool cv[4];
    #pragma unroll
    for (int i = 0; i < 4; ++i) {
        int ar = m0 + wr * 64 + i * 16 + lr;
        aP[i] = hrb + (size_t)ar * KD + lk;
        int nr = n0 + wc * 64 + i * 16 + lr;
        cg[i] = nr; cv[i] = nr < NE;
        bPf[i] = entf + (size_t)(cv[i] ? nr : 0) * KD + lk;
    }

    f32x4 acc[4][4];
    #pragma unroll
    for (int m = 0; m < 4; ++m)
        #pragma unroll
        for (int n = 0; n < 4; ++n)
            acc[m][n] = (f32x4){0.f, 0.f, 0.f, 0.f};

    #pragma unroll
    for (int ks = 0; ks < KD / 32; ++ks) {
        bf16x8 af[4], bfr[4];
        #pragma unroll
        for (int i = 0; i < 4; ++i)
            af[i] = *(const bf16x8*)(aP[i] + ks * 32);
        #pragma unroll
        for (int i = 0; i < 4; ++i) {
            const float4* p = (const float4*)(bPf[i] + ks * 32);
            bfr[i] = pack8(p[0], p[1]);
        }
        #pragma unroll
        for (int m = 0; m < 4; ++m)
            #pragma unroll
            for (int n = 0; n < 4; ++n)
                acc[m][n] = __builtin_amdgcn_mfma_f32_16x16x32_bf16(af[m], bfr[n], acc[m][n], 0, 0, 0);
    }

    float eq[4];
    #pragma unroll
    for (int n = 0; n < 4; ++n) eq[n] = cv[n] ? entsq[cg[n]] : 0.f;

    unsigned long long rowbest[4][4];
    #pragma unroll
    for (int m = 0; m < 4; ++m) {
        #pragma unroll
        for (int j = 0; j < 4; ++j) {
            int rg = m0 + wr * 64 + m * 16 + ((lane >> 4) << 2) + j;
            float hqv = hrsq[rg];
            size_t ro = (size_t)rg * NE;
            unsigned long long best = 0ull;
            #pragma unroll
            for (int n = 0; n < 4; ++n) {
                if (cv[n]) {
                    float s = 2.0f * acc[m][n][j] - hqv - eq[n];
                    out[ro + cg[n]] = s;
                    unsigned long long k64 = packkey(s, cg[n]);
                    best = (k64 > best) ? k64 : best;
                }
            }
            #pragma unroll
            for (int off = 8; off > 0; off >>= 1) {
                unsigned long long o =
                    (unsigned long long)__shfl_xor((long long)best, off, 16);
                best = (o > best) ? o : best;
            }
            rowbest[m][j] = best;
        }
    }
    if (lr == 0) {
        int gg = lane >> 4;
        #pragma unroll
        for (int m = 0; m < 4; ++m)
            #pragma unroll
            for (int j = 0; j < 4; ++j)
                lds_best[wc][wr * 64 + m * 16 + gg * 4 + j] = rowbest[m][j];
    }
    __syncthreads();
    if (tid < 128) {
        unsigned long long a = lds_best[0][tid];
        unsigned long long b = lds_best[1][tid];
        unsigned long long best = a > b ? a : b;
        part[(size_t)(m0 + tid) * PSTRIDE + nt] = best;
    }
}

// ---- reduce: per row, max over NP partials -> prediction ----
__global__ __launch_bounds__(256) void reduce_kernel(const unsigned long long* __restrict__ part,
                                                     float* __restrict__ pred, int np) {
    __shared__ unsigned long long sb[256];
    int row = blockIdx.x;
    int tid = threadIdx.x;
    const unsigned long long* base = part + (size_t)row * PSTRIDE;
    unsigned long long best = 0ull;
    for (int i = tid; i < np; i += 256) {
        unsigned long long v = base[i];
        best = v > best ? v : best;
    }
    sb[tid] = best;
    __syncthreads();
    #pragma unroll
    for (int s = 128; s > 0; s >>= 1) {
        if (tid < s) {
            unsigned long long o = sb[tid + s];
            if (o > sb[tid]) sb[tid] = o;
        }
        __syncthreads();
    }
    if (tid == 0) {
        unsigned int ic = (unsigned int)(sb[0] & 0xFFFFFFFFull);
        pred[row] = (float)(~ic);
    }
}

extern "C" void kernel_launch(void* const* d_in, const int* in_sizes, int n_in,
                              void* d_out, int out_size, void* d_ws, size_t ws_size,
                              hipStream_t stream) {
    const int*   q   = (const int*)d_in[0];
    const float* ent = (const float*)d_in[1];
    const float* rel = (const float*)d_in[2];
    float* out = (float*)d_out;
    char*  ws  = (char*)d_ws;

    unsigned short*     hrb   = (unsigned short*)ws;
    float*              hrsq  = (float*)(ws + WS_HRSQ);
    float*              entsq = (float*)(ws + WS_ENTSQ);
    unsigned long long* part  = (unsigned long long*)(ws + WS_PART);
    unsigned short*     entb  = (unsigned short*)(ws + WS_ENTB);
    float* pred = out + (size_t)MM * NE;

    prep_kernel<<<MM, 64, 0, stream>>>(q, ent, rel, hrb, hrsq);

    if (ws_size >= WS_NEED) {
        conv_entsq_kernel<<<12500, 256, 0, stream>>>(ent, entb, entsq);
        gemm_v10<<<64 * NSTRIP, 512, 0, stream>>>(hrb, entb, hrsq, entsq, out, part);
        reduce_kernel<<<MM, 256, 0, stream>>>(part, pred, NSTRIP);
    } else {
        entsq_kernel<<<(NE + 3) / 4, 256, 0, stream>>>(ent, entsq);
        gemm_direct_f32<<<8 * NT, 256, 0, stream>>>(hrb, ent, hrsq, entsq, out, part);
        reduce_kernel<<<MM, 256, 0, stream>>>(part, pred, NT);
    }
}

// Round 13
// 171.277 us; speedup vs baseline: 3.0239x; 3.0239x over previous
//
#include <hip/hip_runtime.h>

#define MM 1024
#define NE 100000
#define KD 256
#define NT 782       // fallback tiling
#define NTILE 1563   // ceil(NE/64)
#define PSTRIDE 784

typedef __attribute__((ext_vector_type(8))) short bf16x8;
typedef __attribute__((ext_vector_type(4))) float f32x4;
typedef __attribute__((ext_vector_type(4))) short short4v;

// ws layout (bytes):
//   [0, 524288)            hr bf16      1024*256*2
//   [524288, 528384)       hr_sq f32    1024
//   [528384, 928384)       ent_sq f32   100000
//   [1048576, 7471104)     argmax partials u64 [1024][784]
//   [8388608, +51.2MB)     ent bf16     100000*256*2   (tier A only)
#define WS_HRSQ   524288
#define WS_ENTSQ  528384
#define WS_PART   1048576
#define WS_ENTB   8388608
#define WS_NEED   (WS_ENTB + (size_t)NE * KD * 2)

#define AS1 __attribute__((address_space(1)))
#define AS3 __attribute__((address_space(3)))

__device__ __forceinline__ void gld_lds16(const void* g, void* l) {
    __builtin_amdgcn_global_load_lds((const AS1 unsigned int*)g,
                                     (AS3 unsigned int*)l, 16, 0, 0);
}

__device__ __forceinline__ unsigned short f2bf(float f) {
    union { float f; unsigned int u; } v; v.f = f;
    unsigned int u = v.u;
    return (unsigned short)((u + 0x7FFFu + ((u >> 16) & 1u)) >> 16);
}

__device__ __forceinline__ bf16x8 pack8(float4 a, float4 b) {
    bf16x8 t;
    t[0] = (short)f2bf(a.x); t[1] = (short)f2bf(a.y);
    t[2] = (short)f2bf(a.z); t[3] = (short)f2bf(a.w);
    t[4] = (short)f2bf(b.x); t[5] = (short)f2bf(b.y);
    t[6] = (short)f2bf(b.z); t[7] = (short)f2bf(b.w);
    return t;
}

// monotonic pack: bigger score -> bigger key; ties -> smaller col wins
__device__ __forceinline__ unsigned long long packkey(float s, int col) {
    unsigned int u = __float_as_uint(s);
    unsigned int key = u ^ ((unsigned int)((int)u >> 31) | 0x80000000u);
    return ((unsigned long long)key << 32) | (unsigned int)(~col);
}

// ---- prep: hr = E[head] + R[rel] -> bf16; hr_sq ----
__global__ __launch_bounds__(64) void prep_kernel(const int* __restrict__ q,
                                                  const float* __restrict__ ent,
                                                  const float* __restrict__ rel,
                                                  unsigned short* __restrict__ hrb,
                                                  float* __restrict__ hrsq) {
    int b = blockIdx.x;
    int lane = threadIdx.x;
    int head = q[b * 3 + 0];
    int r    = q[b * 3 + 1];
    float4 e  = ((const float4*)(ent + (size_t)head * KD))[lane];
    float4 rv = ((const float4*)(rel + (size_t)r * KD))[lane];
    float4 h; h.x = e.x + rv.x; h.y = e.y + rv.y; h.z = e.z + rv.z; h.w = e.w + rv.w;
    short4v hv;
    hv[0] = (short)f2bf(h.x); hv[1] = (short)f2bf(h.y);
    hv[2] = (short)f2bf(h.z); hv[3] = (short)f2bf(h.w);
    *(short4v*)(hrb + (size_t)b * KD + lane * 4) = hv;
    float sq = h.x * h.x + h.y * h.y + h.z * h.z + h.w * h.w;
    #pragma unroll
    for (int off = 32; off > 0; off >>= 1) sq += __shfl_down(sq, off, 64);
    if (lane == 0) hrsq[b] = sq;
}

// ---- fused: ent f32 -> bf16 + ent_sq ----
__global__ __launch_bounds__(256) void conv_entsq_kernel(const float* __restrict__ ent,
                                                         unsigned short* __restrict__ entb,
                                                         float* __restrict__ entsq) {
    int gw   = (blockIdx.x * 256 + threadIdx.x) >> 6;
    int lane = threadIdx.x & 63;
    int row  = gw * 2 + (lane >> 5);
    if (row >= NE) return;
    const float4* src = (const float4*)(ent + (size_t)row * KD) + (lane & 31) * 2;
    float4 a = src[0], b = src[1];
    *(bf16x8*)(entb + (size_t)row * KD + (lane & 31) * 8) = pack8(a, b);
    float s = a.x * a.x + a.y * a.y + a.z * a.z + a.w * a.w
            + b.x * b.x + b.y * b.y + b.z * b.z + b.w * b.w;
    #pragma unroll
    for (int off = 16; off > 0; off >>= 1) s += __shfl_xor(s, off, 64);
    if ((lane & 31) == 0) entsq[row] = s;
}

// ---- ent_sq only (fallback path) ----
__global__ __launch_bounds__(256) void entsq_kernel(const float* __restrict__ ent,
                                                    float* __restrict__ entsq) {
    int w = threadIdx.x >> 6, lane = threadIdx.x & 63;
    int n = blockIdx.x * 4 + w;
    if (n >= NE) return;
    float4 v = ((const float4*)(ent + (size_t)n * KD))[lane];
    float s = v.x * v.x + v.y * v.y + v.z * v.z + v.w * v.w;
    #pragma unroll
    for (int off = 32; off > 0; off >>= 1) s += __shfl_down(s, off, 64);
    if (lane == 0) entsq[n] = s;
}

// ---- GEMM v13: v12 with the macro-shadowing bug fixed (PAR evaluated
//      BEFORE the inner staging loop; inner loop var renamed).
//      Entity tiles (64e x 512B = 32KB) staged via global_load_lds dbuf;
//      hr fragments in registers; one __syncthreads per tile; swapped
//      operands -> f32x4 wide stores; XCD-co-located lock-step groups. ----
__global__ __launch_bounds__(256, 2) void gemm_v13(const unsigned short* __restrict__ hrb,
                                                   const unsigned short* __restrict__ entb,
                                                   const float* __restrict__ hrsq,
                                                   const float* __restrict__ entsq,
                                                   float* __restrict__ out,
                                                   unsigned long long* __restrict__ part) {
    __shared__ __align__(16) char SMEM[65536];   // 2 x 32KB entity tile dbuf

    const int bid    = blockIdx.x;
    const int qpanel = bid >> 6;       // 8 panels of 128 queries
    const int g      = bid & 63;       // tile group; bid%8 = g%8 -> same XCD
    const int q0     = qpanel * 128;

    const int tid  = threadIdx.x;
    const int lane = tid & 63;
    const int wid  = tid >> 6;
    const int lr = lane & 15;
    const int lg = lane >> 4;
    const int qw = q0 + wid * 32;      // this wave's 32 queries

    const int nT = (NTILE - g + 63) >> 6;

    // ---- per-wave query constants + hr fragments in registers ----
    float hq[2]; unsigned qoff[2];
    #pragma unroll
    for (int nn = 0; nn < 2; ++nn) {
        int qq = qw + nn * 16 + lr;
        hq[nn] = hrsq[qq];
        qoff[nn] = (unsigned)qq * (unsigned)NE;
    }
    bf16x8 bq[8][2];   // [ks][nn], 64 VGPR
    #pragma unroll
    for (int ks = 0; ks < 8; ++ks)
        #pragma unroll
        for (int nn = 0; nn < 2; ++nn)
            bq[ks][nn] = *(const bf16x8*)(hrb + (size_t)(qw + nn * 16 + lr) * KD
                                          + ks * 32 + lg * 8);

    // ---- staging: 8 x gld_lds(16B) per wave, inverse-swizzled source.
    //      HYGIENE: evaluate T/PAR into locals BEFORE the inner loop (the
    //      R11/R12 NaN bug was PAR="(i+1)&1" captured by the INNER i). ----
    const char* ebB = (const char*)entb;
    #define STAGE_TILE(T, PAR)                                                  \
    {                                                                           \
        const int e0s_  = (T) * 64;                                            \
        char* dbase_ = SMEM + (PAR) * 32768 + wid * 8192;                       \
        _Pragma("unroll")                                                       \
        for (int si_ = 0; si_ < 8; ++si_) {                                     \
            int L_ = wid * 8192 + si_ * 1024 + lane * 16;                       \
            int row_ = L_ >> 9;                                                 \
            int Gx_ = L_ ^ ((row_ & 7) << 4);                                   \
            int er_ = e0s_ + row_; er_ = er_ < NE ? er_ : (NE - 1);             \
            gld_lds16(ebB + (size_t)er_ * 512 + (Gx_ & 511),                    \
                      dbase_ + si_ * 1024);                                     \
        }                                                                       \
    }

    // prologue: stage tile g into buf0; sync drains it
    STAGE_TILE(g, 0);

    float bestf[2]; int bestc[2];
    #pragma unroll
    for (int nn = 0; nn < 2; ++nn) { bestf[nn] = -3.4e38f; bestc[nn] = 0; }

    __syncthreads();

    for (int i = 0; i < nT; ++i) {
        const int t = g + (i << 6);

        // issue next tile's staging early (fire-and-forget)
        if (i + 1 < nT) STAGE_TILE(t + 64, (i + 1) & 1);

        const char* buf = SMEM + (i & 1) * 32768;
        f32x4 acc[4][2];
        #pragma unroll
        for (int mm = 0; mm < 4; ++mm)
            #pragma unroll
            for (int nn = 0; nn < 2; ++nn)
                acc[mm][nn] = (f32x4){0.f, 0.f, 0.f, 0.f};

        #pragma unroll
        for (int ks = 0; ks < 8; ++ks) {
            bf16x8 af[4];
            #pragma unroll
            for (int mm = 0; mm < 4; ++mm) {
                int r = mm * 16 + lr;
                int byte = r * 512 + ((ks * 64 + lg * 16) ^ ((r & 7) << 4));
                af[mm] = *(const bf16x8*)(buf + byte);
            }
            #pragma unroll
            for (int mm = 0; mm < 4; ++mm)
                #pragma unroll
                for (int nn = 0; nn < 2; ++nn)
                    acc[mm][nn] = __builtin_amdgcn_mfma_f32_16x16x32_bf16(af[mm], bq[ks][nn], acc[mm][nn], 0, 0, 0);
        }

        // ---- epilogue: wide f32x4 stores + register argmax ----
        const int e0 = t * 64;
        #pragma unroll
        for (int mm = 0; mm < 4; ++mm) {
            const int eb = e0 + mm * 16 + lg * 4;
            if (eb < NE) {
                const float4 eq = *(const float4*)(entsq + eb);
                #pragma unroll
                for (int nn = 0; nn < 2; ++nn) {
                    float4 sv;
                    sv.x = 2.0f * acc[mm][nn][0] - hq[nn] - eq.x;
                    sv.y = 2.0f * acc[mm][nn][1] - hq[nn] - eq.y;
                    sv.z = 2.0f * acc[mm][nn][2] - hq[nn] - eq.z;
                    sv.w = 2.0f * acc[mm][nn][3] - hq[nn] - eq.w;
                    *(float4*)(out + qoff[nn] + (unsigned)eb) = sv;
                    if (sv.x > bestf[nn]) { bestf[nn] = sv.x; bestc[nn] = eb; }
                    if (sv.y > bestf[nn]) { bestf[nn] = sv.y; bestc[nn] = eb + 1; }
                    if (sv.z > bestf[nn]) { bestf[nn] = sv.z; bestc[nn] = eb + 2; }
                    if (sv.w > bestf[nn]) { bestf[nn] = sv.w; bestc[nn] = eb + 3; }
                }
            }
        }

        __syncthreads();   // stage(t+64) done; buf reads done before overwrite
    }

    // ---- argmax: reduce across the 4 lg-lanes of each (nn,lr) query ----
    #pragma unroll
    for (int nn = 0; nn < 2; ++nn) {
        unsigned long long best = packkey(bestf[nn], bestc[nn]);
        #pragma unroll
        for (int off = 16; off <= 32; off <<= 1) {
            unsigned long long o =
                (unsigned long long)__shfl_xor((long long)best, off, 64);
            best = (o > best) ? o : best;
        }
        if (lg == 0)
            part[(size_t)(qw + nn * 16 + lr) * PSTRIDE + g] = best;
    }
    #undef STAGE_TILE
}

// ---- fallback GEMM (B from f32 directly), atomic-free partials ----
__global__ __launch_bounds__(256, 3) void gemm_direct_f32(const unsigned short* __restrict__ hrb,
                                                          const float* __restrict__ entf,
                                                          const float* __restrict__ hrsq,
                                                          const float* __restrict__ entsq,
                                                          float* __restrict__ out,
                                                          unsigned long long* __restrict__ part) {
    __shared__ unsigned long long lds_best[2][128];
    const int bid  = blockIdx.x;
    const int wgid = (bid & 7) * NT + (bid >> 3);
    const int mt = wgid & 7, nt = wgid >> 3;
    const int m0 = mt * 128, n0 = nt * 128;
    const int tid  = threadIdx.x;
    const int lane = tid & 63;
    const int wid  = tid >> 6;
    const int wr = wid >> 1, wc = wid & 1;
    const int lr = lane & 15;
    const int lk = (lane >> 4) * 8;

    const unsigned short* aP[4];
    const float*          bPf[4];
    int  cg[4];
    bool cv[4];
    #pragma unroll
    for (int i = 0; i < 4; ++i) {
        int ar = m0 + wr * 64 + i * 16 + lr;
        aP[i] = hrb + (size_t)ar * KD + lk;
        int nr = n0 + wc * 64 + i * 16 + lr;
        cg[i] = nr; cv[i] = nr < NE;
        bPf[i] = entf + (size_t)(cv[i] ? nr : 0) * KD + lk;
    }

    f32x4 acc[4][4];
    #pragma unroll
    for (int m = 0; m < 4; ++m)
        #pragma unroll
        for (int n = 0; n < 4; ++n)
            acc[m][n] = (f32x4){0.f, 0.f, 0.f, 0.f};

    #pragma unroll
    for (int ks = 0; ks < KD / 32; ++ks) {
        bf16x8 af[4], bfr[4];
        #pragma unroll
        for (int i = 0; i < 4; ++i)
            af[i] = *(const bf16x8*)(aP[i] + ks * 32);
        #pragma unroll
        for (int i = 0; i < 4; ++i) {
            const float4* p = (const float4*)(bPf[i] + ks * 32);
            bfr[i] = pack8(p[0], p[1]);
        }
        #pragma unroll
        for (int m = 0; m < 4; ++m)
            #pragma unroll
            for (int n = 0; n < 4; ++n)
                acc[m][n] = __builtin_amdgcn_mfma_f32_16x16x32_bf16(af[m], bfr[n], acc[m][n], 0, 0, 0);
    }

    float eq[4];
    #pragma unroll
    for (int n = 0; n < 4; ++n) eq[n] = cv[n] ? entsq[cg[n]] : 0.f;

    unsigned long long rowbest[4][4];
    #pragma unroll
    for (int m = 0; m < 4; ++m) {
        #pragma unroll
        for (int j = 0; j < 4; ++j) {
            int rg = m0 + wr * 64 + m * 16 + ((lane >> 4) << 2) + j;
            float hqv = hrsq[rg];
            size_t ro = (size_t)rg * NE;
            unsigned long long best = 0ull;
            #pragma unroll
            for (int n = 0; n < 4; ++n) {
                if (cv[n]) {
                    float s = 2.0f * acc[m][n][j] - hqv - eq[n];
                    out[ro + cg[n]] = s;
                    unsigned long long k64 = packkey(s, cg[n]);
                    best = (k64 > best) ? k64 : best;
                }
            }
            #pragma unroll
            for (int off = 8; off > 0; off >>= 1) {
                unsigned long long o =
                    (unsigned long long)__shfl_xor((long long)best, off, 16);
                best = (o > best) ? o : best;
            }
            rowbest[m][j] = best;
        }
    }
    if (lr == 0) {
        int gg = lane >> 4;
        #pragma unroll
        for (int m = 0; m < 4; ++m)
            #pragma unroll
            for (int j = 0; j < 4; ++j)
                lds_best[wc][wr * 64 + m * 16 + gg * 4 + j] = rowbest[m][j];
    }
    __syncthreads();
    if (tid < 128) {
        unsigned long long a = lds_best[0][tid];
        unsigned long long b = lds_best[1][tid];
        unsigned long long best = a > b ? a : b;
        part[(size_t)(m0 + tid) * PSTRIDE + nt] = best;
    }
}

// ---- reduce: per row, max over NP partials -> prediction ----
__global__ __launch_bounds__(256) void reduce_kernel(const unsigned long long* __restrict__ part,
                                                     float* __restrict__ pred, int np) {
    __shared__ unsigned long long sb[256];
    int row = blockIdx.x;
    int tid = threadIdx.x;
    const unsigned long long* base = part + (size_t)row * PSTRIDE;
    unsigned long long best = 0ull;
    for (int i = tid; i < np; i += 256) {
        unsigned long long v = base[i];
        best = v > best ? v : best;
    }
    sb[tid] = best;
    __syncthreads();
    #pragma unroll
    for (int s = 128; s > 0; s >>= 1) {
        if (tid < s) {
            unsigned long long o = sb[tid + s];
            if (o > sb[tid]) sb[tid] = o;
        }
        __syncthreads();
    }
    if (tid == 0) {
        unsigned int ic = (unsigned int)(sb[0] & 0xFFFFFFFFull);
        pred[row] = (float)(~ic);
    }
}

extern "C" void kernel_launch(void* const* d_in, const int* in_sizes, int n_in,
                              void* d_out, int out_size, void* d_ws, size_t ws_size,
                              hipStream_t stream) {
    const int*   q   = (const int*)d_in[0];
    const float* ent = (const float*)d_in[1];
    const float* rel = (const float*)d_in[2];
    float* out = (float*)d_out;
    char*  ws  = (char*)d_ws;

    unsigned short*     hrb   = (unsigned short*)ws;
    float*              hrsq  = (float*)(ws + WS_HRSQ);
    float*              entsq = (float*)(ws + WS_ENTSQ);
    unsigned long long* part  = (unsigned long long*)(ws + WS_PART);
    unsigned short*     entb  = (unsigned short*)(ws + WS_ENTB);
    float* pred = out + (size_t)MM * NE;

    prep_kernel<<<MM, 64, 0, stream>>>(q, ent, rel, hrb, hrsq);

    if (ws_size >= WS_NEED) {
        conv_entsq_kernel<<<12500, 256, 0, stream>>>(ent, entb, entsq);
        gemm_v13<<<8 * 64, 256, 0, stream>>>(hrb, entb, hrsq, entsq, out, part);
        reduce_kernel<<<MM, 256, 0, stream>>>(part, pred, 64);
    } else {
        entsq_kernel<<<(NE + 3) / 4, 256, 0, stream>>>(ent, entsq);
        gemm_direct_f32<<<8 * NT, 256, 0, stream>>>(hrb, ent, hrsq, entsq, out, part);
        reduce_kernel<<<MM, 256, 0, stream>>>(part, pred, NT);
    }
}

// Round 14
// 165.746 us; speedup vs baseline: 3.1248x; 1.0334x over previous
//
#include <hip/hip_runtime.h>

#define MM 1024
#define NE 100000
#define KD 256
#define NT 782       // fallback tiling
#define NTILE 1563   // ceil(NE/64)
#define PSTRIDE 784

typedef __attribute__((ext_vector_type(8))) short bf16x8;
typedef __attribute__((ext_vector_type(4))) float f32x4;
typedef __attribute__((ext_vector_type(4))) short short4v;

// ws layout (bytes):
//   [0, 524288)            hr bf16      1024*256*2
//   [524288, 528384)       hr_sq f32    1024
//   [528384, 928384)       ent_sq f32   100000
//   [1048576, 7471104)     argmax partials u64 [1024][784]
//   [8388608, +51.2MB)     ent bf16     100000*256*2   (tier A only)
#define WS_HRSQ   524288
#define WS_ENTSQ  528384
#define WS_PART   1048576
#define WS_ENTB   8388608
#define WS_NEED   (WS_ENTB + (size_t)NE * KD * 2)

#define AS1 __attribute__((address_space(1)))
#define AS3 __attribute__((address_space(3)))

__device__ __forceinline__ void gld_lds16(const void* g, void* l) {
    __builtin_amdgcn_global_load_lds((const AS1 unsigned int*)g,
                                     (AS3 unsigned int*)l, 16, 0, 0);
}

__device__ __forceinline__ unsigned short f2bf(float f) {
    union { float f; unsigned int u; } v; v.f = f;
    unsigned int u = v.u;
    return (unsigned short)((u + 0x7FFFu + ((u >> 16) & 1u)) >> 16);
}

__device__ __forceinline__ bf16x8 pack8(float4 a, float4 b) {
    bf16x8 t;
    t[0] = (short)f2bf(a.x); t[1] = (short)f2bf(a.y);
    t[2] = (short)f2bf(a.z); t[3] = (short)f2bf(a.w);
    t[4] = (short)f2bf(b.x); t[5] = (short)f2bf(b.y);
    t[6] = (short)f2bf(b.z); t[7] = (short)f2bf(b.w);
    return t;
}

// monotonic pack: bigger score -> bigger key; ties -> smaller col wins
__device__ __forceinline__ unsigned long long packkey(float s, int col) {
    unsigned int u = __float_as_uint(s);
    unsigned int key = u ^ ((unsigned int)((int)u >> 31) | 0x80000000u);
    return ((unsigned long long)key << 32) | (unsigned int)(~col);
}

// ---- prep: hr = E[head] + R[rel] -> bf16; hr_sq ----
__global__ __launch_bounds__(64) void prep_kernel(const int* __restrict__ q,
                                                  const float* __restrict__ ent,
                                                  const float* __restrict__ rel,
                                                  unsigned short* __restrict__ hrb,
                                                  float* __restrict__ hrsq) {
    int b = blockIdx.x;
    int lane = threadIdx.x;
    int head = q[b * 3 + 0];
    int r    = q[b * 3 + 1];
    float4 e  = ((const float4*)(ent + (size_t)head * KD))[lane];
    float4 rv = ((const float4*)(rel + (size_t)r * KD))[lane];
    float4 h; h.x = e.x + rv.x; h.y = e.y + rv.y; h.z = e.z + rv.z; h.w = e.w + rv.w;
    short4v hv;
    hv[0] = (short)f2bf(h.x); hv[1] = (short)f2bf(h.y);
    hv[2] = (short)f2bf(h.z); hv[3] = (short)f2bf(h.w);
    *(short4v*)(hrb + (size_t)b * KD + lane * 4) = hv;
    float sq = h.x * h.x + h.y * h.y + h.z * h.z + h.w * h.w;
    #pragma unroll
    for (int off = 32; off > 0; off >>= 1) sq += __shfl_down(sq, off, 64);
    if (lane == 0) hrsq[b] = sq;
}

// ---- fused: ent f32 -> bf16 + ent_sq ----
__global__ __launch_bounds__(256) void conv_entsq_kernel(const float* __restrict__ ent,
                                                         unsigned short* __restrict__ entb,
                                                         float* __restrict__ entsq) {
    int gw   = (blockIdx.x * 256 + threadIdx.x) >> 6;
    int lane = threadIdx.x & 63;
    int row  = gw * 2 + (lane >> 5);
    if (row >= NE) return;
    const float4* src = (const float4*)(ent + (size_t)row * KD) + (lane & 31) * 2;
    float4 a = src[0], b = src[1];
    *(bf16x8*)(entb + (size_t)row * KD + (lane & 31) * 8) = pack8(a, b);
    float s = a.x * a.x + a.y * a.y + a.z * a.z + a.w * a.w
            + b.x * b.x + b.y * b.y + b.z * b.z + b.w * b.w;
    #pragma unroll
    for (int off = 16; off > 0; off >>= 1) s += __shfl_xor(s, off, 64);
    if ((lane & 31) == 0) entsq[row] = s;
}

// ---- ent_sq only (fallback path) ----
__global__ __launch_bounds__(256) void entsq_kernel(const float* __restrict__ ent,
                                                    float* __restrict__ entsq) {
    int w = threadIdx.x >> 6, lane = threadIdx.x & 63;
    int n = blockIdx.x * 4 + w;
    if (n >= NE) return;
    float4 v = ((const float4*)(ent + (size_t)n * KD))[lane];
    float s = v.x * v.x + v.y * v.y + v.z * v.z + v.w * v.w;
    #pragma unroll
    for (int off = 32; off > 0; off >>= 1) s += __shfl_down(s, off, 64);
    if (lane == 0) entsq[n] = s;
}

// ---- GEMM v14: v13 with stores moved AFTER the per-tile barrier.
//      Stores read only registers, so LDS ordering doesn't need them before
//      the barrier; issuing them after gives a full tile of runway before
//      the next barrier's vmcnt(0) drain -> store latency off the critical
//      path. eq (entsq) loads hoisted before compute for the same reason. ----
__global__ __launch_bounds__(256, 2) void gemm_v14(const unsigned short* __restrict__ hrb,
                                                   const unsigned short* __restrict__ entb,
                                                   const float* __restrict__ hrsq,
                                                   const float* __restrict__ entsq,
                                                   float* __restrict__ out,
                                                   unsigned long long* __restrict__ part) {
    __shared__ __align__(16) char SMEM[65536];   // 2 x 32KB entity tile dbuf

    const int bid    = blockIdx.x;
    const int qpanel = bid >> 6;       // 8 panels of 128 queries
    const int g      = bid & 63;       // tile group; bid%8 = g%8 -> same XCD
    const int q0     = qpanel * 128;

    const int tid  = threadIdx.x;
    const int lane = tid & 63;
    const int wid  = tid >> 6;
    const int lr = lane & 15;
    const int lg = lane >> 4;
    const int qw = q0 + wid * 32;      // this wave's 32 queries

    const int nT = (NTILE - g + 63) >> 6;

    // ---- per-wave query constants + hr fragments in registers ----
    float hq[2]; unsigned qoff[2];
    #pragma unroll
    for (int nn = 0; nn < 2; ++nn) {
        int qq = qw + nn * 16 + lr;
        hq[nn] = hrsq[qq];
        qoff[nn] = (unsigned)qq * (unsigned)NE;
    }
    bf16x8 bq[8][2];   // [ks][nn], 64 VGPR
    #pragma unroll
    for (int ks = 0; ks < 8; ++ks)
        #pragma unroll
        for (int nn = 0; nn < 2; ++nn)
            bq[ks][nn] = *(const bf16x8*)(hrb + (size_t)(qw + nn * 16 + lr) * KD
                                          + ks * 32 + lg * 8);

    // ---- staging: 8 x gld_lds(16B) per wave (hygienic macro, R12 lesson) ----
    const char* ebB = (const char*)entb;
    #define STAGE_TILE(T, PAR)                                                  \
    {                                                                           \
        const int e0s_  = (T) * 64;                                            \
        char* dbase_ = SMEM + (PAR) * 32768 + wid * 8192;                       \
        _Pragma("unroll")                                                       \
        for (int si_ = 0; si_ < 8; ++si_) {                                     \
            int L_ = wid * 8192 + si_ * 1024 + lane * 16;                       \
            int row_ = L_ >> 9;                                                 \
            int Gx_ = L_ ^ ((row_ & 7) << 4);                                   \
            int er_ = e0s_ + row_; er_ = er_ < NE ? er_ : (NE - 1);             \
            gld_lds16(ebB + (size_t)er_ * 512 + (Gx_ & 511),                    \
                      dbase_ + si_ * 1024);                                     \
        }                                                                       \
    }

    // prologue: stage tile g into buf0; sync drains it
    STAGE_TILE(g, 0);

    float bestf[2]; int bestc[2];
    #pragma unroll
    for (int nn = 0; nn < 2; ++nn) { bestf[nn] = -3.4e38f; bestc[nn] = 0; }

    __syncthreads();

    for (int i = 0; i < nT; ++i) {
        const int t = g + (i << 6);
        const int e0 = t * 64;

        // issue next tile's staging early (fire-and-forget)
        if (i + 1 < nT) STAGE_TILE(t + 64, (i + 1) & 1);

        // hoist eq loads: retire during compute, cheap at the barrier drain
        float4 eqv[4];
        #pragma unroll
        for (int mm = 0; mm < 4; ++mm) {
            int ebq = e0 + mm * 16 + lg * 4;
            ebq = ebq < (NE - 4) ? ebq : (NE - 4);
            eqv[mm] = *(const float4*)(entsq + ebq);
        }

        const char* buf = SMEM + (i & 1) * 32768;
        f32x4 acc[4][2];
        #pragma unroll
        for (int mm = 0; mm < 4; ++mm)
            #pragma unroll
            for (int nn = 0; nn < 2; ++nn)
                acc[mm][nn] = (f32x4){0.f, 0.f, 0.f, 0.f};

        #pragma unroll
        for (int ks = 0; ks < 8; ++ks) {
            bf16x8 af[4];
            #pragma unroll
            for (int mm = 0; mm < 4; ++mm) {
                int r = mm * 16 + lr;
                int byte = r * 512 + ((ks * 64 + lg * 16) ^ ((r & 7) << 4));
                af[mm] = *(const bf16x8*)(buf + byte);
            }
            #pragma unroll
            for (int mm = 0; mm < 4; ++mm)
                #pragma unroll
                for (int nn = 0; nn < 2; ++nn)
                    acc[mm][nn] = __builtin_amdgcn_mfma_f32_16x16x32_bf16(af[mm], bq[ks][nn], acc[mm][nn], 0, 0, 0);
        }

        // barrier BEFORE stores: ensures stage(t+64) landed and all waves'
        // LDS reads of buf are done; drains prior-tile stores that have had
        // a full tile of runway. Stores below then fly during the next tile.
        __syncthreads();

        // ---- epilogue: wide f32x4 stores + register argmax (post-barrier) ----
        #pragma unroll
        for (int mm = 0; mm < 4; ++mm) {
            const int eb = e0 + mm * 16 + lg * 4;
            if (eb < NE) {
                const float4 eq = eqv[mm];
                #pragma unroll
                for (int nn = 0; nn < 2; ++nn) {
                    float4 sv;
                    sv.x = 2.0f * acc[mm][nn][0] - hq[nn] - eq.x;
                    sv.y = 2.0f * acc[mm][nn][1] - hq[nn] - eq.y;
                    sv.z = 2.0f * acc[mm][nn][2] - hq[nn] - eq.z;
                    sv.w = 2.0f * acc[mm][nn][3] - hq[nn] - eq.w;
                    *(float4*)(out + qoff[nn] + (unsigned)eb) = sv;
                    if (sv.x > bestf[nn]) { bestf[nn] = sv.x; bestc[nn] = eb; }
                    if (sv.y > bestf[nn]) { bestf[nn] = sv.y; bestc[nn] = eb + 1; }
                    if (sv.z > bestf[nn]) { bestf[nn] = sv.z; bestc[nn] = eb + 2; }
                    if (sv.w > bestf[nn]) { bestf[nn] = sv.w; bestc[nn] = eb + 3; }
                }
            }
        }
    }

    // ---- argmax: reduce across the 4 lg-lanes of each (nn,lr) query ----
    #pragma unroll
    for (int nn = 0; nn < 2; ++nn) {
        unsigned long long best = packkey(bestf[nn], bestc[nn]);
        #pragma unroll
        for (int off = 16; off <= 32; off <<= 1) {
            unsigned long long o =
                (unsigned long long)__shfl_xor((long long)best, off, 64);
            best = (o > best) ? o : best;
        }
        if (lg == 0)
            part[(size_t)(qw + nn * 16 + lr) * PSTRIDE + g] = best;
    }
    #undef STAGE_TILE
}

// ---- fallback GEMM (B from f32 directly), atomic-free partials ----
__global__ __launch_bounds__(256, 3) void gemm_direct_f32(const unsigned short* __restrict__ hrb,
                                                          const float* __restrict__ entf,
                                                          const float* __restrict__ hrsq,
                                                          const float* __restrict__ entsq,
                                                          float* __restrict__ out,
                                                          unsigned long long* __restrict__ part) {
    __shared__ unsigned long long lds_best[2][128];
    const int bid  = blockIdx.x;
    const int wgid = (bid & 7) * NT + (bid >> 3);
    const int mt = wgid & 7, nt = wgid >> 3;
    const int m0 = mt * 128, n0 = nt * 128;
    const int tid  = threadIdx.x;
    const int lane = tid & 63;
    const int wid  = tid >> 6;
    const int wr = wid >> 1, wc = wid & 1;
    const int lr = lane & 15;
    const int lk = (lane >> 4) * 8;

    const unsigned short* aP[4];
    const float*          bPf[4];
    int  cg[4];
    bool cv[4];
    #pragma unroll
    for (int i = 0; i < 4; ++i) {
        int ar = m0 + wr * 64 + i * 16 + lr;
        aP[i] = hrb + (size_t)ar * KD + lk;
        int nr = n0 + wc * 64 + i * 16 + lr;
        cg[i] = nr; cv[i] = nr < NE;
        bPf[i] = entf + (size_t)(cv[i] ? nr : 0) * KD + lk;
    }

    f32x4 acc[4][4];
    #pragma unroll
    for (int m = 0; m < 4; ++m)
        #pragma unroll
        for (int n = 0; n < 4; ++n)
            acc[m][n] = (f32x4){0.f, 0.f, 0.f, 0.f};

    #pragma unroll
    for (int ks = 0; ks < KD / 32; ++ks) {
        bf16x8 af[4], bfr[4];
        #pragma unroll
        for (int i = 0; i < 4; ++i)
            af[i] = *(const bf16x8*)(aP[i] + ks * 32);
        #pragma unroll
        for (int i = 0; i < 4; ++i) {
            const float4* p = (const float4*)(bPf[i] + ks * 32);
            bfr[i] = pack8(p[0], p[1]);
        }
        #pragma unroll
        for (int m = 0; m < 4; ++m)
            #pragma unroll
            for (int n = 0; n < 4; ++n)
                acc[m][n] = __builtin_amdgcn_mfma_f32_16x16x32_bf16(af[m], bfr[n], acc[m][n], 0, 0, 0);
    }

    float eq[4];
    #pragma unroll
    for (int n = 0; n < 4; ++n) eq[n] = cv[n] ? entsq[cg[n]] : 0.f;

    unsigned long long rowbest[4][4];
    #pragma unroll
    for (int m = 0; m < 4; ++m) {
        #pragma unroll
        for (int j = 0; j < 4; ++j) {
            int rg = m0 + wr * 64 + m * 16 + ((lane >> 4) << 2) + j;
            float hqv = hrsq[rg];
            size_t ro = (size_t)rg * NE;
            unsigned long long best = 0ull;
            #pragma unroll
            for (int n = 0; n < 4; ++n) {
                if (cv[n]) {
                    float s = 2.0f * acc[m][n][j] - hqv - eq[n];
                    out[ro + cg[n]] = s;
                    unsigned long long k64 = packkey(s, cg[n]);
                    best = (k64 > best) ? k64 : best;
                }
            }
            #pragma unroll
            for (int off = 8; off > 0; off >>= 1) {
                unsigned long long o =
                    (unsigned long long)__shfl_xor((long long)best, off, 16);
                best = (o > best) ? o : best;
            }
            rowbest[m][j] = best;
        }
    }
    if (lr == 0) {
        int gg = lane >> 4;
        #pragma unroll
        for (int m = 0; m < 4; ++m)
            #pragma unroll
            for (int j = 0; j < 4; ++j)
                lds_best[wc][wr * 64 + m * 16 + gg * 4 + j] = rowbest[m][j];
    }
    __syncthreads();
    if (tid < 128) {
        unsigned long long a = lds_best[0][tid];
        unsigned long long b = lds_best[1][tid];
        unsigned long long best = a > b ? a : b;
        part[(size_t)(m0 + tid) * PSTRIDE + nt] = best;
    }
}

// ---- reduce: per row, max over NP partials -> prediction ----
__global__ __launch_bounds__(256) void reduce_kernel(const unsigned long long* __restrict__ part,
                                                     float* __restrict__ pred, int np) {
    __shared__ unsigned long long sb[256];
    int row = blockIdx.x;
    int tid = threadIdx.x;
    const unsigned long long* base = part + (size_t)row * PSTRIDE;
    unsigned long long best = 0ull;
    for (int i = tid; i < np; i += 256) {
        unsigned long long v = base[i];
        best = v > best ? v : best;
    }
    sb[tid] = best;
    __syncthreads();
    #pragma unroll
    for (int s = 128; s > 0; s >>= 1) {
        if (tid < s) {
            unsigned long long o = sb[tid + s];
            if (o > sb[tid]) sb[tid] = o;
        }
        __syncthreads();
    }
    if (tid == 0) {
        unsigned int ic = (unsigned int)(sb[0] & 0xFFFFFFFFull);
        pred[row] = (float)(~ic);
    }
}

extern "C" void kernel_launch(void* const* d_in, const int* in_sizes, int n_in,
                              void* d_out, int out_size, void* d_ws, size_t ws_size,
                              hipStream_t stream) {
    const int*   q   = (const int*)d_in[0];
    const float* ent = (const float*)d_in[1];
    const float* rel = (const float*)d_in[2];
    float* out = (float*)d_out;
    char*  ws  = (char*)d_ws;

    unsigned short*     hrb   = (unsigned short*)ws;
    float*              hrsq  = (float*)(ws + WS_HRSQ);
    float*              entsq = (float*)(ws + WS_ENTSQ);
    unsigned long long* part  = (unsigned long long*)(ws + WS_PART);
    unsigned short*     entb  = (unsigned short*)(ws + WS_ENTB);
    float* pred = out + (size_t)MM * NE;

    prep_kernel<<<MM, 64, 0, stream>>>(q, ent, rel, hrb, hrsq);

    if (ws_size >= WS_NEED) {
        conv_entsq_kernel<<<12500, 256, 0, stream>>>(ent, entb, entsq);
        gemm_v14<<<8 * 64, 256, 0, stream>>>(hrb, entb, hrsq, entsq, out, part);
        reduce_kernel<<<MM, 256, 0, stream>>>(part, pred, 64);
    } else {
        entsq_kernel<<<(NE + 3) / 4, 256, 0, stream>>>(ent, entsq);
        gemm_direct_f32<<<8 * NT, 256, 0, stream>>>(hrb, ent, hrsq, entsq, out, part);
        reduce_kernel<<<MM, 256, 0, stream>>>(part, pred, NT);
    }
}